// Round 7
// baseline (108.840 us; speedup 1.0000x reference)
//
#include <hip/hip_runtime.h>
#include <math.h>

#define NTOT   12
#define DIM    4096      // 2^12
#define LAYERS 4
#define NB     1024      // batch
#define SPAD   4608      // phys(i) = i + 2*(i>>4); max 4095+510 = 4605

typedef float v2f __attribute__((ext_vector_type(2)));

// Fused (Ry*Rx) SU(2) gate on local bit G of a 16-amp register block, complex
// interleaved (lo=re, hi=im). Coefficients packed: P1=(cc,cs), P2=(ss,sc).
// 8 v_pk_*_f32 per pair; swaps/negs via op_sel / neg modifiers.
template<int G>
__device__ __forceinline__ void gate_pk(v2f (&x)[16], v2f P1, v2f P2) {
#pragma unroll
    for (int p = 0; p < 8; ++p) {
        const int j0 = ((p >> G) << (G + 1)) | (p & ((1 << G) - 1));
        const int j1 = j0 | (1 << G);
        const v2f x0 = x[j0], x1 = x[j1];
        v2f t, u;
        asm("v_pk_mul_f32 %0, %1, %2 op_sel:[1,1] op_sel_hi:[1,0] neg_hi:[1,0]"
            : "=v"(t) : "v"(P2), "v"(x1));
        asm("v_pk_fma_f32 %0, %1, %2, %0 op_sel:[1,0,0] op_sel_hi:[1,1,1] neg_lo:[1,0,0] neg_hi:[1,0,0]"
            : "+v"(t) : "v"(P1), "v"(x1));
        asm("v_pk_fma_f32 %0, %1, %2, %0 op_sel:[0,1,0] op_sel_hi:[0,0,1] neg_lo:[1,0,0]"
            : "+v"(t) : "v"(P2), "v"(x0));
        asm("v_pk_fma_f32 %0, %1, %2, %0 op_sel:[0,0,0] op_sel_hi:[0,1,1]"
            : "+v"(t) : "v"(P1), "v"(x0));
        asm("v_pk_mul_f32 %0, %1, %2 op_sel:[0,1] op_sel_hi:[0,0] neg_hi:[1,0]"
            : "=v"(u) : "v"(P2), "v"(x1));
        asm("v_pk_fma_f32 %0, %1, %2, %0 op_sel:[0,0,0] op_sel_hi:[0,1,1]"
            : "+v"(u) : "v"(P1), "v"(x1));
        asm("v_pk_fma_f32 %0, %1, %2, %0 op_sel:[1,1,0] op_sel_hi:[1,0,1] neg_hi:[1,0,0]"
            : "+v"(u) : "v"(P2), "v"(x0));
        asm("v_pk_fma_f32 %0, %1, %2, %0 op_sel:[1,0,0] op_sel_hi:[1,1,1]"
            : "+v"(u) : "v"(P1), "v"(x0));
        x[j0] = t; x[j1] = u;
    }
}

// Apply the 4 gates of one partition-group of one layer.
__device__ __forceinline__ void apply4(v2f (&x)[16], const float4* gco, int base) {
    float4 c;
    c = gco[base + 3]; gate_pk<0>(x, (v2f){c.x, c.y}, (v2f){c.z, c.w});
    c = gco[base + 2]; gate_pk<1>(x, (v2f){c.x, c.y}, (v2f){c.z, c.w});
    c = gco[base + 1]; gate_pk<2>(x, (v2f){c.x, c.y}, (v2f){c.z, c.w});
    c = gco[base + 0]; gate_pk<3>(x, (v2f){c.x, c.y}, (v2f){c.z, c.w});
}

// CZ diagonal: flip sign bits via precomputed xor words (0 or 0x80000000).
__device__ __forceinline__ void applyCZ(v2f (&x)[16], const int (&sw)[16]) {
#pragma unroll
    for (int j = 0; j < 16; ++j) {
        x[j].x = __uint_as_float(__float_as_uint(x[j].x) ^ sw[j]);
        x[j].y = __uint_as_float(__float_as_uint(x[j].y) ^ sw[j]);
    }
}

// Padded layout: phys(i) = i + 2*(i>>4). Partitions:
//   C: thread t holds amps t*16+j        (regs = bits 3:0)  -> WAVE-LOCAL
//   B: thread t holds (t>>4)*256+j*16+(t&15) (regs = bits 7:4) -> WAVE-LOCAL
//   A: thread t holds j*256+t            (regs = bits 11:8) -> inter-wave
// C and B slots of wave w both lie in S[1152w .. 1152w+1152): C<->B exchanges
// need NO __syncthreads (same-wave RAW via lgkmcnt). Only B<->A exchanges and
// the final output gather need block barriers: 5 barriers total (was 10).
__global__ __launch_bounds__(256, 4) void qddpm_kernel(
    const float* __restrict__ in_re,
    const float* __restrict__ in_im,
    const float* __restrict__ params,
    const float* __restrict__ uu,
    float* __restrict__ out)
{
    __shared__ v2f    S[SPAD];         // 36 KB, interleaved (re,im), padded layout
    __shared__ float4 gco[48];         // per-gate (cc, cs, ss, sc), g = lay*12+q
    __shared__ float  sprob[16];

    const int b = blockIdx.x;
    const int t = threadIdx.x;
    const float uval = uu[b];

    // per-thread bases (v2f element indices)
    const int baseA = t + 2 * (t >> 4);            // A: S[baseA + 288*j]
    const int baseB = (t >> 4) * 288 + (t & 15);   // B: S[baseB + 18*j]
    const int baseC = t * 18;                      // C: S[baseC + j] (contiguous)

    v2f x[16];

    // ---- direct global -> registers, C-partition (64 contiguous B per array) ----
    {
        const float4* re4 = (const float4*)(in_re + (size_t)b * DIM + t * 16);
        const float4* im4 = (const float4*)(in_im + (size_t)b * DIM + t * 16);
#pragma unroll
        for (int q = 0; q < 4; ++q) {
            const float4 vr = re4[q];
            const float4 vi = im4[q];
            x[4 * q + 0] = (v2f){vr.x, vi.x};
            x[4 * q + 1] = (v2f){vr.y, vi.y};
            x[4 * q + 2] = (v2f){vr.z, vi.z};
            x[4 * q + 3] = (v2f){vr.w, vi.w};
        }
    }

    // ---- gate coefficients: computed REDUNDANTLY by every wave (identical
    // values -> benign duplicate LDS writes; each wave reads after its own
    // write via lgkmcnt => no barrier needed) ----
    {
        const int lg = t & 63;
        if (lg < 48) {                   // gate (lay = lg/12, q = lg%12)
            const int lay = lg / 12, q = lg - lay * 12;
            float c1, s1, c2, s2;
            sincosf(params[lay * 24 + q] * 0.5f, &s1, &c1);
            sincosf(params[lay * 24 + 12 + q] * 0.5f, &s2, &c2);
            gco[lg] = make_float4(c1 * c2, c1 * s2, s1 * s2, s1 * c2); // (cc,cs,ss,sc)
        }
    }

    // CZ sign-bit xor words for A- and C-partition amps
    int swA[16], swC[16];
#pragma unroll
    for (int j = 0; j < 16; ++j) {
        const int iC = t * 16 + j;
        swC[j] = (__popc(iC & (iC >> 1) & 0x7FF) & 1) << 31;
        const int iA = j * 256 + t;
        swA[j] = (__popc(iA & (iA >> 1) & 0x7FF) & 1) << 31;
    }

    // ---- C0 (q8..11, layer0) from registers ----
    apply4(x, gco, 0 * 12 + 8);
    {
        float4* dst = (float4*)(S + baseC);
#pragma unroll
        for (int q = 0; q < 8; ++q)
            dst[q] = make_float4(x[2 * q].x, x[2 * q].y, x[2 * q + 1].x, x[2 * q + 1].y);
    }
    // no barrier: C->B is wave-local

    // ---- B0 (q4..7, layer0) ----
#pragma unroll
    for (int j = 0; j < 16; ++j) x[j] = S[baseB + 18 * j];
    apply4(x, gco, 0 * 12 + 4);
#pragma unroll
    for (int j = 0; j < 16; ++j) S[baseB + 18 * j] = x[j];
    __syncthreads();                     // (1) B -> A (inter-wave)

    // ---- A0 + CZ0 + A1 ----
#pragma unroll
    for (int j = 0; j < 16; ++j) x[j] = S[baseA + 288 * j];
    apply4(x, gco, 0 * 12 + 0);
    applyCZ(x, swA);
    apply4(x, gco, 1 * 12 + 0);
#pragma unroll
    for (int j = 0; j < 16; ++j) S[baseA + 288 * j] = x[j];
    __syncthreads();                     // (2) A -> B (inter-wave)

    // ---- B1 ----
#pragma unroll
    for (int j = 0; j < 16; ++j) x[j] = S[baseB + 18 * j];
    apply4(x, gco, 1 * 12 + 4);
#pragma unroll
    for (int j = 0; j < 16; ++j) S[baseB + 18 * j] = x[j];
    // no barrier: B->C wave-local

    // ---- C1 + CZ1 + C2 ----
    {
        const float4* src = (const float4*)(S + baseC);
#pragma unroll
        for (int q = 0; q < 8; ++q) {
            const float4 v = src[q];
            x[2 * q]     = (v2f){v.x, v.y};
            x[2 * q + 1] = (v2f){v.z, v.w};
        }
    }
    apply4(x, gco, 1 * 12 + 8);
    applyCZ(x, swC);
    apply4(x, gco, 2 * 12 + 8);
    {
        float4* dst = (float4*)(S + baseC);
#pragma unroll
        for (int q = 0; q < 8; ++q)
            dst[q] = make_float4(x[2 * q].x, x[2 * q].y, x[2 * q + 1].x, x[2 * q + 1].y);
    }
    // no barrier: C->B wave-local

    // ---- B2 ----
#pragma unroll
    for (int j = 0; j < 16; ++j) x[j] = S[baseB + 18 * j];
    apply4(x, gco, 2 * 12 + 4);
#pragma unroll
    for (int j = 0; j < 16; ++j) S[baseB + 18 * j] = x[j];
    __syncthreads();                     // (3) B -> A

    // ---- A2 + CZ2 + A3 ----
#pragma unroll
    for (int j = 0; j < 16; ++j) x[j] = S[baseA + 288 * j];
    apply4(x, gco, 2 * 12 + 0);
    applyCZ(x, swA);
    apply4(x, gco, 3 * 12 + 0);
#pragma unroll
    for (int j = 0; j < 16; ++j) S[baseA + 288 * j] = x[j];
    __syncthreads();                     // (4) A -> B

    // ---- B3 ----
#pragma unroll
    for (int j = 0; j < 16; ++j) x[j] = S[baseB + 18 * j];
    apply4(x, gco, 3 * 12 + 4);
#pragma unroll
    for (int j = 0; j < 16; ++j) S[baseB + 18 * j] = x[j];
    // no barrier: B->C wave-local

    // ---- C3 + CZ3 + probs ----
    {
        const float4* src = (const float4*)(S + baseC);
#pragma unroll
        for (int q = 0; q < 8; ++q) {
            const float4 v = src[q];
            x[2 * q]     = (v2f){v.x, v.y};
            x[2 * q + 1] = (v2f){v.z, v.w};
        }
    }
    apply4(x, gco, 3 * 12 + 8);
    applyCZ(x, swC);
    {
        v2f acc2 = (v2f){0.0f, 0.0f};
#pragma unroll
        for (int j = 0; j < 16; ++j) acc2 += x[j] * x[j];
        float4* dst = (float4*)(S + baseC);
#pragma unroll
        for (int q = 0; q < 8; ++q)
            dst[q] = make_float4(x[2 * q].x, x[2 * q].y, x[2 * q + 1].x, x[2 * q + 1].y);
        // this thread's 16 amps (i = t*16+j) all belong to ancilla outcome t>>4
        float partial = acc2.x + acc2.y;
#pragma unroll
        for (int o = 8; o > 0; o >>= 1)
            partial += __shfl_down(partial, o, 16);
        if ((t & 15) == 0) sprob[t >> 4] = partial;
    }
    __syncthreads();                     // (5) S + sprob ready block-wide

    // ---- redundant per-thread inverse-CDF sample + output [B, 256, 2] ----
    {
        float cdf[16];
        float a = 0.0f;
#pragma unroll
        for (int i = 0; i < 16; ++i) { a += sprob[i]; cdf[i] = a; }
        const float thresh = uval * a;
        int m = 0;
#pragma unroll
        for (int i = 15; i >= 0; --i) { if (cdf[i] >= thresh) m = i; }
        const float rn = 1.0f / sqrtf(sprob[m]);
        const v2f amp = S[baseA + 288 * m];     // phys(m*256 + t), A-pattern
        ((float2*)out)[(size_t)b * 256 + t] = make_float2(amp.x * rn, amp.y * rn);
    }
}

extern "C" void kernel_launch(void* const* d_in, const int* in_sizes, int n_in,
                              void* d_out, int out_size, void* d_ws, size_t ws_size,
                              hipStream_t stream) {
    const float* in_re  = (const float*)d_in[0];
    const float* in_im  = (const float*)d_in[1];
    const float* params = (const float*)d_in[2];
    const float* u      = (const float*)d_in[3];
    float* out = (float*)d_out;
    qddpm_kernel<<<NB, 256, 0, stream>>>(in_re, in_im, params, u, out);
}